// Round 11
// baseline (86560.767 us; speedup 1.0000x reference)
//
#include <hip/hip_runtime.h>
#include <stdint.h>

// BinaryAttention on MI355X (gfx950).  B=64, N=197, C=768, H=12, d=64.
//
// ROUND 11 — F64 PRE-QUANTIZATION PIPELINE (close the 2.87e-3 -> <2.22e-3 gap).
// R10 established: orientation flag + stride family CORRECT (0.167 -> 2.9e-3),
// inputs fp32, output fp32. Residual error = quantization boundary flips from
// fp32 noise (expf ~1e-6 -> ~15k P-flips; GEMM sum noise -> sign/v flips) vs
// the f64 numpy reference. Fix: all values feeding sign()/round() computed in
// f64; quantized domains kept exact-integer.
//
//   1) qkv_f64: per-element f64 dot + fused epilogue:
//        q/k: sign ballot -> bitmask; wave-reduced f64 |.| -> f64 atomicAdd
//        v:   f64 quantize -> int8
//   2) attn_f64: logits = coef64 * (64-2*popc(q^k)) + bias (exact int dot);
//        f64 softmax (parallel exp, serial deterministic max/sum);
//        P = rint(p/(1/255)) clip -> u8; PV exact int; attnf f64
//   3) proj_f64: f64 dot + bias -> fp32 out (flag-strided)

#define NT 197
#define HH 12
#define CD 768
#define NB 64
#define MROWS (NB * NT)   // 12608
#define NBH (NB * HH)     // 768

// ---- flag-selected flat indexers (flag: 0 = C-order, 1 = F-order) ----
__device__ __forceinline__ size_t idxX(int f, int b, int n, int c) {
  return f ? ((size_t)b + 64u * (size_t)n + 12608u * (size_t)c)
           : ((size_t)(b * NT + n) * CD + c);
}
__device__ __forceinline__ size_t idxW3(int f, int r, int c) {  // qkv_w [2304,768]
  return f ? ((size_t)r + 2304u * (size_t)c) : ((size_t)r * CD + c);
}
__device__ __forceinline__ size_t idxWP(int f, int r, int c) {  // proj_w [768,768]
  return f ? ((size_t)r + 768u * (size_t)c) : ((size_t)r * CD + c);
}
__device__ __forceinline__ size_t idxRT(int f, int i, int h) {  // rel_table [732,12]
  return f ? ((size_t)i + 732u * (size_t)h) : ((size_t)i * HH + h);
}
__device__ __forceinline__ size_t idxRI(int f, int n, int m) {  // rel_index [197,197]
  return f ? ((size_t)n + 197u * (size_t)m) : ((size_t)n * NT + m);
}

// ---- orientation probe (deterministic rel_index: C: ri[1]=729, ri[197]=730) --
__global__ __launch_bounds__(64) void probe_orient(const int* __restrict__ ri,
                                                   int* __restrict__ flag) {
  if (threadIdx.x == 0) {
    const int a = ri[1], b = ri[197];
    flag[0] = (a == 730 && b == 729) ? 1 : 0;
  }
}

__global__ __launch_bounds__(256) void zero_k(float* __restrict__ p) {
  p[blockIdx.x * 256 + threadIdx.x] = 0.0f;
}

// ---------- 1) qkv GEMM in f64 + fused quantize epilogue ----------
// grid (9, 12608), block 256. c = kind*768 + h*64 + dd; each wave = one head.
__global__ __launch_bounds__(256) void qkv_f64(
    const float* __restrict__ x, const float* __restrict__ w,
    uint64_t* __restrict__ qbits, uint64_t* __restrict__ kbits,
    int8_t* __restrict__ vq8, double* __restrict__ sqa,
    double* __restrict__ ska, const int* __restrict__ flag) {
  const int f = flag[0];
  const int c = blockIdx.x * 256 + threadIdx.x;   // 0..2303
  const int row = blockIdx.y;                     // 0..12607
  const int b = row / NT, n = row - b * NT;

  double acc = 0.0;
  for (int k = 0; k < CD; k++)
    acc += (double)x[idxX(f, b, n, k)] * (double)w[idxW3(f, c, k)];

  const int kind = c / CD;               // 0=q,1=k,2=v (uniform per block)
  const int h = (c % CD) / 64;           // uniform per wave
  const int lane = threadIdx.x & 63;     // == dd
  const int bh = b * HH + h;

  if (kind == 2) {
    const double sV = 2.0 / 127.0;
    double vc = fmin(fmax(acc, -2.0), 2.0);
    double vq = rint(vc / sV);
    vq = fmin(fmax(vq, -127.0), 127.0);
    vq8[(size_t)(bh * NT + n) * 64 + lane] = (int8_t)(int)vq;
  } else {
    const uint64_t msk = __ballot(acc < 0.0);   // bit dd = 1 iff negative
    double a = fabs(acc);
    #pragma unroll
    for (int off = 1; off < 64; off <<= 1) a += __shfl_xor(a, off);
    if (lane == 0) {
      if (kind == 0) { qbits[bh * NT + n] = msk; atomicAdd(&sqa[bh], a); }
      else           { kbits[bh * NT + n] = msk; atomicAdd(&ska[bh], a); }
    }
  }
}

// ---------- 2) attention in f64: one block per (b,h,n) ----------
// grid (197, 768), block 256.
__global__ __launch_bounds__(256) void attn_f64(
    const uint64_t* __restrict__ qbits, const uint64_t* __restrict__ kbits,
    const int8_t* __restrict__ vq8, const double* __restrict__ sqa,
    const double* __restrict__ ska, const float* __restrict__ rel_table,
    const int* __restrict__ rel_index, double* __restrict__ attnf,
    const int* __restrict__ flag) {
  __shared__ double ls[NT];
  __shared__ double es[NT];
  __shared__ double red[2];      // [0]=max, [1]=sum
  __shared__ int Pu[NT];

  const int f = flag[0];
  const int n = blockIdx.x;
  const int bh = blockIdx.y;
  const int b = bh / HH, h = bh % HH;
  const int t = threadIdx.x;

  const double s_q = sqa[bh] / (double)(NT * 64);
  const double s_k = ska[bh] / (double)(NT * 64);
  const double coef = s_q * s_k * 0.125;
  const uint64_t qb = qbits[(size_t)bh * NT + n];
  const uint64_t* kb = kbits + (size_t)bh * NT;

  if (t < NT) {
    const int m = t;
    const int dot = 64 - 2 * (int)__popcll(qb ^ kb[m]);
    ls[m] = coef * (double)dot +
            (double)rel_table[idxRT(f, rel_index[idxRI(f, n, m)], h)];
  }
  __syncthreads();

  if (t == 0) {
    double mx = ls[0];
    for (int m = 1; m < NT; m++) mx = fmax(mx, ls[m]);
    red[0] = mx;
  }
  __syncthreads();
  if (t < NT) es[t] = exp(ls[t] - red[0]);   // parallel f64 exp
  __syncthreads();
  if (t == 0) {
    double s = 0.0;
    for (int m = 0; m < NT; m++) s += es[m];
    red[1] = s;
  }
  __syncthreads();
  if (t < NT) {
    const double sP = 1.0 / 255.0;
    double P = rint((es[t] / red[1]) / sP);
    P = fmin(fmax(P, 0.0), 255.0);
    Pu[t] = (int)P;
  }
  __syncthreads();

  // PV: thread dd<64, exact int dot over m
  if (t < 64) {
    const int dd = t;
    const int8_t* vb = vq8 + (size_t)bh * NT * 64 + dd;
    int acc = 0;
    for (int m = 0; m < NT; m++) acc += Pu[m] * (int)vb[(size_t)m * 64];
    const double sP = 1.0 / 255.0, sV = 2.0 / 127.0;
    attnf[(size_t)(b * NT + n) * CD + h * 64 + dd] = (double)acc * sP * sV;
  }
}

// ---------- 3) proj GEMM in f64 -> fp32 out ----------
// grid (3, 12608), block 256.
__global__ __launch_bounds__(256) void proj_f64(
    const double* __restrict__ attnf, const float* __restrict__ w,
    const float* __restrict__ bias, float* __restrict__ out,
    const int* __restrict__ flag) {
  const int f = flag[0];
  const int c = blockIdx.x * 256 + threadIdx.x;   // 0..767
  const int row = blockIdx.y;
  const int b = row / NT, n = row - b * NT;
  const double* ar = attnf + (size_t)row * CD;
  double acc = 0.0;
  for (int k = 0; k < CD; k++)
    acc += ar[k] * (double)w[idxWP(f, c, k)];
  out[idxX(f, b, n, c)] = (float)(acc + (double)bias[c]);
}

// ---------------- host launch ----------------
extern "C" void kernel_launch(void* const* d_in, const int* in_sizes, int n_in,
                              void* d_out, int out_size, void* d_ws, size_t ws_size,
                              hipStream_t stream) {
  (void)out_size; (void)ws_size;

  // resolve inputs BY ELEMENT COUNT (all unique; fallback positional)
  const float* x = nullptr;
  const float* qkv_w = nullptr;
  const float* proj_w = nullptr;
  const float* proj_b = nullptr;
  const float* rel_table = nullptr;
  const int* rel_index = nullptr;
  for (int i = 0; i < n_in; i++) {
    switch (in_sizes[i]) {
      case 9682944: x         = (const float*)d_in[i]; break;
      case 1769472: qkv_w     = (const float*)d_in[i]; break;
      case 589824:  proj_w    = (const float*)d_in[i]; break;
      case 768:     proj_b    = (const float*)d_in[i]; break;
      case 8784:    rel_table = (const float*)d_in[i]; break;
      case 38809:   rel_index = (const int*)d_in[i];   break;
      default: break;
    }
  }
  if (!x)         x         = (const float*)d_in[0];
  if (!qkv_w)     qkv_w     = (const float*)d_in[1];
  if (!proj_w)    proj_w    = (const float*)d_in[2];
  if (!proj_b)    proj_b    = (const float*)d_in[3];
  if (!rel_table) rel_table = (const float*)d_in[4];
  if (!rel_index) rel_index = (const int*)d_in[5];
  float* out = (float*)d_out;   // FP32 output (established R10)

  uint8_t* ws = (uint8_t*)d_ws;
  // workspace (~90 MB):
  int*      flag  = (int*)(ws + 0);             //         64
  double*   sqa   = (double*)(ws + 64);         //      6,144
  double*   ska   = (double*)(ws + 6208);       //      6,144
  uint64_t* qbits = (uint64_t*)(ws + 12352);    //  1,210,368
  uint64_t* kbits = (uint64_t*)(ws + 1222720);  //  1,210,368
  int8_t*   vq8   = (int8_t*)(ws + 2433088);    //  9,682,944
  double*   attnf = (double*)(ws + 12116032);   // 77,463,552 -> 89,579,584

  probe_orient<<<1, 64, 0, stream>>>(rel_index, flag);
  zero_k<<<12, 256, 0, stream>>>((float*)sqa);   // zero sqa+ska (12,288 B)

  qkv_f64<<<dim3(9, MROWS), 256, 0, stream>>>(x, qkv_w, qbits, kbits, vq8,
                                              sqa, ska, flag);
  attn_f64<<<dim3(NT, NBH), 256, 0, stream>>>(qbits, kbits, vq8, sqa, ska,
                                              rel_table, rel_index, attnf, flag);
  proj_f64<<<dim3(3, MROWS), 256, 0, stream>>>(attnf, proj_w, proj_b, out, flag);
}